// Round 17
// baseline (180.753 us; speedup 1.0000x reference)
//
#include <hip/hip_runtime.h>
#include <hip/hip_bf16.h>

typedef __attribute__((ext_vector_type(8))) short short8;
typedef __attribute__((ext_vector_type(4))) float floatx4;

__device__ __forceinline__ ushort f2bf(float f) {
    union { __hip_bfloat16 h; ushort u; } cv;
    cv.h = __float2bfloat16(f);
    return cv.u;
}
__device__ __forceinline__ float bf2f(ushort u) {
    union { ushort u; __hip_bfloat16 h; } cv;
    cv.u = u;
    return __bfloat162float(cv.h);
}
// truncating f32->bf16 (RTZ): 1 shr. Used for P only (bias cancels in softmax ratio).
__device__ __forceinline__ ushort f2bf_rtz(float f) {
    union { float f; unsigned u; } cv;
    cv.f = f;
    return (ushort)(cv.u >> 16);
}

typedef __attribute__((address_space(1))) void* gas1_t;
typedef __attribute__((address_space(3))) void* las3_t;
// async global->LDS, 16B per lane. LDS dest = wave-uniform base + lane*16.
__device__ __forceinline__ void cp16(const ushort* g, ushort* l) {
    __builtin_amdgcn_global_load_lds((gas1_t)(unsigned long long)g,
                                     (las3_t)(unsigned long long)l, 16, 0, 0);
}

// ---------------------------------------------------------------------------
// Kernel 1: MERGED weight-transpose + LayerNorm (both indep preprocessing).
// ---------------------------------------------------------------------------
__global__ __launch_bounds__(256) void prep_w_ln(const float* __restrict__ Wqkv,
                                                 const float* __restrict__ Wout,
                                                 ushort* __restrict__ WqkvT,
                                                 ushort* __restrict__ WoutT,
                                                 const float* __restrict__ x,
                                                 const float* __restrict__ lw,
                                                 const float* __restrict__ lb,
                                                 ushort* __restrict__ xn) {
    const int id = blockIdx.x;
    const int tid = threadIdx.x;
    if (id < 4096) {
        __shared__ float tile[32][33];
        int bx = id & 127, by = id >> 7;
        const float* in; ushort* out; int R = 1024, C;
        if (bx < 96) { in = Wqkv; out = WqkvT; C = 3072; }
        else { in = Wout; out = WoutT; C = 1024; bx -= 96; }
        int c0 = bx * 32, r0 = by * 32;
        int tx = tid & 31, ty = tid >> 5;    // 32 x 8
        for (int j = 0; j < 32; j += 8)
            tile[ty + j][tx] = in[(size_t)(r0 + ty + j) * C + c0 + tx];
        __syncthreads();
        for (int j = 0; j < 32; j += 8)
            out[(size_t)(c0 + ty + j) * R + r0 + tx] = f2bf(tile[tx][ty + j]);
    } else {
        int row = id - 4096;
        const float4* xr = (const float4*)(x + (size_t)row * 1024);
        float4 v = xr[tid];
        float s = v.x + v.y + v.z + v.w;
        float sq = v.x * v.x + v.y * v.y + v.z * v.z + v.w * v.w;
        for (int off = 32; off; off >>= 1) {
            s += __shfl_xor(s, off);
            sq += __shfl_xor(sq, off);
        }
        __shared__ float ls[4], lq[4];
        int wave = tid >> 6, lane = tid & 63;
        if (lane == 0) { ls[wave] = s; lq[wave] = sq; }
        __syncthreads();
        s = ls[0] + ls[1] + ls[2] + ls[3];
        sq = lq[0] + lq[1] + lq[2] + lq[3];
        float mu = s * (1.0f / 1024.0f);
        float var = sq * (1.0f / 1024.0f) - mu * mu;
        float rs = rsqrtf(var + 1e-5f);
        const float4* wr = (const float4*)lw;
        const float4* br = (const float4*)lb;
        float4 wv = wr[tid], bv = br[tid];
        ushort4 o;
        o.x = f2bf((v.x - mu) * rs * wv.x + bv.x);
        o.y = f2bf((v.y - mu) * rs * wv.y + bv.y);
        o.z = f2bf((v.z - mu) * rs * wv.z + bv.z);
        o.w = f2bf((v.w - mu) * rs * wv.w + bv.w);
        *(ushort4*)&xn[(size_t)row * 1024 + tid * 4] = o;
    }
}

// ---------------------------------------------------------------------------
// Kernel 2: FUSED QKV GEMM, XCD-striped grid (1-D 768). (unchanged)
// ---------------------------------------------------------------------------
__global__ __launch_bounds__(256) void gemm_qkv_fused(const ushort* __restrict__ A,
                                                      const ushort* __restrict__ Bt,
                                                      ushort* __restrict__ Qt,
                                                      ushort* __restrict__ Kt,
                                                      ushort* __restrict__ Vb) {
    __shared__ ushort smem[18432];
    const int K = 1024, T = 32;
    const int id = blockIdx.x;
    const int xcd = id & 7, r_ = id >> 3;
    const int bm = (xcd * 4 + r_ / 24) * 128;
    const int bn = r_ % 24;
    const int tid = threadIdx.x;
    const int wave = tid >> 6, lane = tid & 63;
    const int quad = lane >> 4, l15 = lane & 15;
    const int wm = (wave >> 1) * 64, wn = (wave & 1) * 64;

    const int s0 = tid, s1 = tid + 256;
    const int row0 = s0 >> 2, src0 = (s0 & 3) ^ (row0 & 3);
    const int row1 = s1 >> 2, src1 = (s1 & 3) ^ (row1 & 3);

    floatx4 acc[4][4];
    floatx4 z4 = {0.f, 0.f, 0.f, 0.f};
    for (int mi = 0; mi < 4; mi++)
        for (int ni = 0; ni < 4; ni++) acc[mi][ni] = z4;

    const ushort* Ap0 = A + (size_t)(bm + row0) * K + src0 * 8;
    const ushort* Ap1 = A + (size_t)(bm + row1) * K + src1 * 8;
    const ushort* Bp0 = Bt + (size_t)(bn * 128 + row0) * K + src0 * 8;
    const ushort* Bp1 = Bt + (size_t)(bn * 128 + row1) * K + src1 * 8;

    ushort* As = smem;          // [2][4096]
    ushort* Bs = smem + 8192;   // [2][4096]

    cp16(Ap0, &As[wave * 512]);
    cp16(Ap1, &As[2048 + wave * 512]);
    cp16(Bp0, &Bs[wave * 512]);
    cp16(Bp1, &Bs[2048 + wave * 512]);

    for (int t = 0; t < T; t++) {
        __syncthreads();
        if (t + 1 < T) {
            const int nb = (t + 1) & 1;
            const int k0n = (t + 1) << 5;
            cp16(Ap0 + k0n, &As[nb * 4096 + wave * 512]);
            cp16(Ap1 + k0n, &As[nb * 4096 + 2048 + wave * 512]);
            cp16(Bp0 + k0n, &Bs[nb * 4096 + wave * 512]);
            cp16(Bp1 + k0n, &Bs[nb * 4096 + 2048 + wave * 512]);
        }
        const ushort* Ab = As + (t & 1) * 4096;
        const ushort* Bb = Bs + (t & 1) * 4096;
        short8 af[4], bfr[4];
        for (int mi = 0; mi < 4; mi++) {
            int ra = wm + mi * 16 + l15;
            af[mi] = *(const short8*)&Ab[ra * 32 + ((quad ^ (ra & 3)) << 3)];
        }
        for (int ni = 0; ni < 4; ni++) {
            int rb = wn + ni * 16 + l15;
            bfr[ni] = *(const short8*)&Bb[rb * 32 + ((quad ^ (rb & 3)) << 3)];
        }
        for (int mi = 0; mi < 4; mi++)
            for (int ni = 0; ni < 4; ni++)
                acc[mi][ni] = __builtin_amdgcn_mfma_f32_16x16x32_bf16(
                    af[mi], bfr[ni], acc[mi][ni], 0, 0, 0);
    }

    const int col_base = bn * 128 + wn;
    const int type = col_base >> 10;             // 0=q, 1=k, 2=v
    const int h = (col_base & 1023) >> 6;
    const int row_base = bm + wm;

    if (type < 2) {
        ushort* dst = (type == 0) ? Qt : Kt;
        for (int mi = 0; mi < 4; mi++) {
            for (int r = 0; r < 4; r++) {
                float ss = 0.f;
                for (int ni = 0; ni < 4; ni++) ss += acc[mi][ni][r] * acc[mi][ni][r];
                for (int off = 1; off < 16; off <<= 1) ss += __shfl_xor(ss, off);
                float inv = rsqrtf(fmaxf(ss, 1e-24f));
                int rg = row_base + mi * 16 + quad * 4 + r;
                int bb = rg >> 11, n = rg & 2047;
                size_t orow = ((size_t)(bb * 16 + h) * 2048 + n) * 64;
                for (int ni = 0; ni < 4; ni++)
                    dst[orow + ni * 16 + l15] = f2bf(acc[mi][ni][r] * inv);
            }
        }
    } else {
        __syncthreads();
        ushort* tr = smem + wave * 4608;   // 64 x 72
        for (int mi = 0; mi < 4; mi++)
            for (int ni = 0; ni < 4; ni++)
                for (int r = 0; r < 4; r++) {
                    int row_l = mi * 16 + quad * 4 + r;   // n_loc
                    int col_l = ni * 16 + l15;            // d
                    tr[col_l * 72 + row_l] = f2bf(acc[mi][ni][r]);
                }
        int bb = row_base >> 11, n0 = row_base & 2047;
        size_t vbase = ((size_t)(bb * 16 + h) * 32 + (n0 >> 6)) * 4096;
        const int dl = lane >> 3, nc = (lane & 7) * 8;
        for (int i = 0; i < 8; i++) {
            int d = dl + i * 8;
            short8 val = *(const short8*)&tr[d * 72 + nc];
            *(short8*)&Vb[vbase + (size_t)d * 64 + nc] = val;
        }
    }
}

// ---------------------------------------------------------------------------
// Kernel 3: MFMA GEMM (out-proj) v2 — 64x64 tiles, grid 1024. (unchanged)
// ---------------------------------------------------------------------------
__global__ __launch_bounds__(256) void gemm_out(const ushort* __restrict__ A,
                                                const ushort* __restrict__ Bt,
                                                float* __restrict__ C) {
    __shared__ ushort As[2][64 * 32];
    __shared__ ushort Bs[2][64 * 32];
    const int K = 1024, N = 1024;
    const int id = blockIdx.x;             // 0..1023
    const int xcd = id & 7, r_ = id >> 3;  // r_ 0..127
    const int bm = (xcd * 8 + (r_ >> 4)) * 64;
    const int bn = (r_ & 15) * 64;
    const int tid = threadIdx.x;
    const int wave = tid >> 6, lane = tid & 63;
    const int quad = lane >> 4, l15 = lane & 15;
    const int wm = (wave >> 1) * 32, wn = (wave & 1) * 32;

    const int row0 = tid >> 2, src0 = (tid & 3) ^ (row0 & 3);

    floatx4 acc[2][2];
    floatx4 z4 = {0.f, 0.f, 0.f, 0.f};
    for (int mi = 0; mi < 2; mi++)
        for (int ni = 0; ni < 2; ni++) acc[mi][ni] = z4;

    const ushort* Ap0 = A + (size_t)(bm + row0) * K + src0 * 8;
    const ushort* Bp0 = Bt + (size_t)(bn + row0) * K + src0 * 8;

    const int T = K >> 5;
    cp16(Ap0, &As[0][wave * 512]);
    cp16(Bp0, &Bs[0][wave * 512]);

    for (int t = 0; t < T; t++) {
        __syncthreads();
        if (t + 1 < T) {
            const int nb = (t + 1) & 1;
            const int k0n = (t + 1) << 5;
            cp16(Ap0 + k0n, &As[nb][wave * 512]);
            cp16(Bp0 + k0n, &Bs[nb][wave * 512]);
        }
        const ushort* Ab = As[t & 1];
        const ushort* Bb = Bs[t & 1];
        short8 af[2], bfr[2];
        for (int mi = 0; mi < 2; mi++) {
            int ra = wm + mi * 16 + l15;
            af[mi] = *(const short8*)&Ab[ra * 32 + ((quad ^ (ra & 3)) << 3)];
        }
        for (int ni = 0; ni < 2; ni++) {
            int rb = wn + ni * 16 + l15;
            bfr[ni] = *(const short8*)&Bb[rb * 32 + ((quad ^ (rb & 3)) << 3)];
        }
        for (int mi = 0; mi < 2; mi++)
            for (int ni = 0; ni < 2; ni++)
                acc[mi][ni] = __builtin_amdgcn_mfma_f32_16x16x32_bf16(
                    af[mi], bfr[ni], acc[mi][ni], 0, 0, 0);
    }
    for (int mi = 0; mi < 2; mi++)
        for (int ni = 0; ni < 2; ni++)
            for (int r = 0; r < 4; r++) {
                int row = bm + wm + mi * 16 + quad * 4 + r;
                int col = bn + wn + ni * 16 + l15;
                C[(size_t)row * N + col] = acc[mi][ni][r];
            }
}

// ---------------------------------------------------------------------------
// Kernel 4: causal flash attention v12 — 128-WIDE K/V STAGES.
// Per-stage kv tile = 128 rows (two 64-blocks) -> exactly 17 stages/block
// (ntiles(i)+ntiles(31-i)=17 for all i), halving barrier+drain crossings vs
// all prior ~45 µs variants (33 stages). Per stage: 16 QK MFMA + 16 PV MFMA
// with doubled intra-stage ILP. LDS 80 KB -> 2 blocks/CU (grid 512, same
// residency as R12 best). Ps: 16x128/wave, 16-chunk XOR swizzle.
// ---------------------------------------------------------------------------
#define LOG2E8 11.541560327111707f   // 8 * log2(e)

__global__ __launch_bounds__(256) void flash_attn(const ushort* __restrict__ Qt,
                                                  const ushort* __restrict__ Kt,
                                                  const ushort* __restrict__ Vb,
                                                  ushort* __restrict__ O) {
    const int id = blockIdx.x;
    const int xcd = id & 7, r_ = id >> 3;
    const int bh = xcd * 4 + (r_ >> 4);
    const int pairi = r_ & 15;
    const int b = bh >> 4, h = bh & 15;
    const int tid = threadIdx.x;
    const int wave = tid >> 6, lane = tid & 63;
    const int quad = lane >> 4, l15 = lane & 15;

    __shared__ ushort Ks[2][128 * 64];   // [kv][d], 8-slot XOR per row
    __shared__ ushort Vs[2][2 * 64 * 64];// [sub][d][kv64], 8-slot XOR per row
    __shared__ ushort Ps[4][16 * 128];   // [qrow][kv], 16-chunk XOR per row

    // staging: 1024 chunks per matrix per 128-tile; thread does 4 each.
    // chunk ch: row = ch>>3, slot = ch&7, content seg = slot ^ (row&7).
    int srow[4], sseg[4];
    for (int i = 0; i < 4; i++) {
        int ch = tid + i * 256;
        srow[i] = ch >> 3;
        sseg[i] = (ch & 7) ^ (srow[i] & 7);
    }
    const ushort* Kp[4];
    const ushort* Vp[4];
    for (int i = 0; i < 4; i++) {
        Kp[i] = Kt + (size_t)bh * 131072 + srow[i] * 64 + sseg[i] * 8;
        // V: chunk ch covers sub = ch>=512, d = (ch>>3)&63; global offset
        // within tile = sub*4096 + d*64 + seg*8 == srow[i]*64 + sseg[i]*8
        Vp[i] = Vb + (size_t)bh * 131072 + srow[i] * 64 + sseg[i] * 8;
    }

    floatx4 z4 = {0.f, 0.f, 0.f, 0.f};

    for (int pass = 0; pass < 2; pass++) {
        const int qt = pass ? (31 - pairi) : pairi;
        const int q0 = qt * 64;
        const int nt = (qt >> 1) + 1;        // 128-wide kv tiles needed

        const ushort* Qp = Qt + ((size_t)bh * 2048 + q0 + wave * 16 + l15) * 64;
        short8 qf0 = *(const short8*)(Qp + quad * 8);
        short8 qf1 = *(const short8*)(Qp + 32 + quad * 8);

        float rs_acc[4] = {0.f, 0.f, 0.f, 0.f};
        floatx4 o_acc[4];
        for (int ni = 0; ni < 4; ni++) o_acc[ni] = z4;

        __syncthreads();  // prior pass's LDS readers done before re-staging buf0
        for (int i = 0; i < 4; i++) {
            cp16(Kp[i], &Ks[0][wave * 512 + i * 2048]);
            cp16(Vp[i], &Vs[0][wave * 512 + i * 2048]);
        }

        for (int j = 0; j < nt; j++) {
            const int kv0 = j * 128;
            __syncthreads();                 // drains cp16(j) -> published
            if (j + 1 < nt) {                // prefetch j+1 during compute
                const int nb2 = (j + 1) & 1;
                const size_t to = (size_t)(j + 1) * 8192;
                for (int i = 0; i < 4; i++) {
                    cp16(Kp[i] + to, &Ks[nb2][wave * 512 + i * 2048]);
                    cp16(Vp[i] + to, &Vs[nb2][wave * 512 + i * 2048]);
                }
            }
            const ushort* Kb = Ks[j & 1];
            const ushort* Vb_ = Vs[j & 1];

            // S = Q K^T over 128 kv rows (8 ni-tiles, independent MFMAs)
            floatx4 s_acc[8];
            for (int ni = 0; ni < 8; ni++) s_acc[ni] = z4;
            for (int ni = 0; ni < 8; ni++) {
                int rb = ni * 16 + l15;
                short8 kf0 = *(const short8*)&Kb[rb * 64 + ((quad ^ (rb & 7)) << 3)];
                short8 kf1 = *(const short8*)&Kb[rb * 64 + (((quad + 4) ^ (rb & 7)) << 3)];
                s_acc[ni] = __builtin_amdgcn_mfma_f32_16x16x32_bf16(qf0, kf0, s_acc[ni], 0, 0, 0);
                s_acc[ni] = __builtin_amdgcn_mfma_f32_16x16x32_bf16(qf1, kf1, s_acc[ni], 0, 0, 0);
            }

            // softmax numerator; mask only on the last tile (all earlier
            // tiles satisfy col <= row for every wave: 128(j+1) <= 64*qt).
            const bool diag = (j == nt - 1);
            for (int ni = 0; ni < 8; ni++) {
                const int col_loc = ni * 16 + l15;
                const int chnk = col_loc >> 3;            // 0..15
                for (int r = 0; r < 4; r++) {
                    const int row_l = quad * 4 + r;       // 0..15
                    float e = __builtin_amdgcn_exp2f(
                        fmaf(s_acc[ni][r], LOG2E8, -LOG2E8));
                    if (diag && kv0 + col_loc > q0 + wave * 16 + row_l) e = 0.f;
                    rs_acc[r] += e;
                    Ps[wave][row_l * 128 + (((chnk ^ row_l) << 3) | (col_loc & 7))] =
                        f2bf_rtz(e);
                }
            }

            // P -> A-layout (4 k-segments of 32), then PV (16 MFMAs)
            short8 pa[4];
            for (int j2 = 0; j2 < 4; j2++)
                pa[j2] = *(const short8*)&Ps[wave][l15 * 128 + (((4 * j2 + quad) ^ l15) << 3)];
            for (int ni = 0; ni < 4; ni++) {
                int rv = ni * 16 + l15;
                for (int j2 = 0; j2 < 4; j2++) {
                    const ushort* vsub = Vb_ + (j2 >> 1) * 4096;
                    short8 v = *(const short8*)&vsub[rv * 64 +
                        ((((j2 & 1) * 4 + quad) ^ (rv & 7)) << 3)];
                    o_acc[ni] = __builtin_amdgcn_mfma_f32_16x16x32_bf16(
                        pa[j2], v, o_acc[ni], 0, 0, 0);
                }
            }
        }

        for (int r = 0; r < 4; r++) {
            float rs = rs_acc[r];
            for (int off = 1; off < 16; off <<= 1) rs += __shfl_xor(rs, off);
            float inv = 1.0f / rs;
            int grow = q0 + wave * 16 + quad * 4 + r;
            size_t rowbase = ((size_t)b * 2048 + grow) * 1024 + h * 64;
            for (int ni = 0; ni < 4; ni++)
                O[rowbase + ni * 16 + l15] = f2bf(o_acc[ni][r] * inv);
        }
    }
}

// ---------------------------------------------------------------------------
extern "C" void kernel_launch(void* const* d_in, const int* in_sizes, int n_in,
                              void* d_out, int out_size, void* d_ws, size_t ws_size,
                              hipStream_t stream) {
    const float* x = (const float*)d_in[0];
    const float* ln_w = (const float*)d_in[1];
    const float* ln_b = (const float*)d_in[2];
    const float* W_qkv = (const float*)d_in[3];
    const float* W_out = (const float*)d_in[4];

    char* w = (char*)d_ws;
    // obuf ALIASES xn: xn is dead after gemm_qkv_fused's last read; flash
    // writes obuf strictly afterwards (stream-ordered). ws = 40 MiB.
    ushort* xn    = (ushort*)(w);                          // 8 MiB
    ushort* obuf  = (ushort*)(w);                          // 8 MiB (alias)
    ushort* WqkvT = (ushort*)(w + (8ull << 20));           // 6 MiB
    ushort* WoutT = (ushort*)(w + (14ull << 20));          // 2 MiB
    ushort* Vb    = (ushort*)(w + (16ull << 20));          // 8 MiB
    ushort* Qt    = (ushort*)(w + (24ull << 20));          // 8 MiB
    ushort* Kt    = (ushort*)(w + (32ull << 20));          // 8 MiB -> 40 MiB total

    prep_w_ln<<<8192, 256, 0, stream>>>(W_qkv, W_out, WqkvT, WoutT, x, ln_w, ln_b, xn);
    gemm_qkv_fused<<<768, 256, 0, stream>>>(xn, WqkvT, Qt, Kt, Vb);
    flash_attn<<<512, 256, 0, stream>>>(Qt, Kt, Vb, obuf);
    gemm_out<<<1024, 256, 0, stream>>>(obuf, WoutT, (float*)d_out);
}

// Round 18
// 176.343 us; speedup vs baseline: 1.0250x; 1.0250x over previous
//
#include <hip/hip_runtime.h>
#include <hip/hip_bf16.h>

typedef __attribute__((ext_vector_type(8))) short short8;
typedef __attribute__((ext_vector_type(4))) float floatx4;

__device__ __forceinline__ ushort f2bf(float f) {
    union { __hip_bfloat16 h; ushort u; } cv;
    cv.h = __float2bfloat16(f);
    return cv.u;
}
__device__ __forceinline__ float bf2f(ushort u) {
    union { ushort u; __hip_bfloat16 h; } cv;
    cv.u = u;
    return __bfloat162float(cv.h);
}
// truncating f32->bf16 (RTZ): 1 shr. Used for P only (bias cancels in softmax ratio).
__device__ __forceinline__ ushort f2bf_rtz(float f) {
    union { float f; unsigned u; } cv;
    cv.f = f;
    return (ushort)(cv.u >> 16);
}

typedef __attribute__((address_space(1))) void* gas1_t;
typedef __attribute__((address_space(3))) void* las3_t;
// async global->LDS, 16B per lane. LDS dest = wave-uniform base + lane*16.
__device__ __forceinline__ void cp16(const ushort* g, ushort* l) {
    __builtin_amdgcn_global_load_lds((gas1_t)(unsigned long long)g,
                                     (las3_t)(unsigned long long)l, 16, 0, 0);
}

// ---------------------------------------------------------------------------
// Kernel 1: MERGED weight-transpose + LayerNorm (both indep preprocessing).
// ---------------------------------------------------------------------------
__global__ __launch_bounds__(256) void prep_w_ln(const float* __restrict__ Wqkv,
                                                 const float* __restrict__ Wout,
                                                 ushort* __restrict__ WqkvT,
                                                 ushort* __restrict__ WoutT,
                                                 const float* __restrict__ x,
                                                 const float* __restrict__ lw,
                                                 const float* __restrict__ lb,
                                                 ushort* __restrict__ xn) {
    const int id = blockIdx.x;
    const int tid = threadIdx.x;
    if (id < 4096) {
        __shared__ float tile[32][33];
        int bx = id & 127, by = id >> 7;
        const float* in; ushort* out; int R = 1024, C;
        if (bx < 96) { in = Wqkv; out = WqkvT; C = 3072; }
        else { in = Wout; out = WoutT; C = 1024; bx -= 96; }
        int c0 = bx * 32, r0 = by * 32;
        int tx = tid & 31, ty = tid >> 5;    // 32 x 8
        for (int j = 0; j < 32; j += 8)
            tile[ty + j][tx] = in[(size_t)(r0 + ty + j) * C + c0 + tx];
        __syncthreads();
        for (int j = 0; j < 32; j += 8)
            out[(size_t)(c0 + ty + j) * R + r0 + tx] = f2bf(tile[tx][ty + j]);
    } else {
        int row = id - 4096;
        const float4* xr = (const float4*)(x + (size_t)row * 1024);
        float4 v = xr[tid];
        float s = v.x + v.y + v.z + v.w;
        float sq = v.x * v.x + v.y * v.y + v.z * v.z + v.w * v.w;
        for (int off = 32; off; off >>= 1) {
            s += __shfl_xor(s, off);
            sq += __shfl_xor(sq, off);
        }
        __shared__ float ls[4], lq[4];
        int wave = tid >> 6, lane = tid & 63;
        if (lane == 0) { ls[wave] = s; lq[wave] = sq; }
        __syncthreads();
        s = ls[0] + ls[1] + ls[2] + ls[3];
        sq = lq[0] + lq[1] + lq[2] + lq[3];
        float mu = s * (1.0f / 1024.0f);
        float var = sq * (1.0f / 1024.0f) - mu * mu;
        float rs = rsqrtf(var + 1e-5f);
        const float4* wr = (const float4*)lw;
        const float4* br = (const float4*)lb;
        float4 wv = wr[tid], bv = br[tid];
        ushort4 o;
        o.x = f2bf((v.x - mu) * rs * wv.x + bv.x);
        o.y = f2bf((v.y - mu) * rs * wv.y + bv.y);
        o.z = f2bf((v.z - mu) * rs * wv.z + bv.z);
        o.w = f2bf((v.w - mu) * rs * wv.w + bv.w);
        *(ushort4*)&xn[(size_t)row * 1024 + tid * 4] = o;
    }
}

// ---------------------------------------------------------------------------
// Kernel 2: FUSED QKV GEMM, XCD-striped grid (1-D 768).
// ---------------------------------------------------------------------------
__global__ __launch_bounds__(256) void gemm_qkv_fused(const ushort* __restrict__ A,
                                                      const ushort* __restrict__ Bt,
                                                      ushort* __restrict__ Qt,
                                                      ushort* __restrict__ Kt,
                                                      ushort* __restrict__ Vb) {
    __shared__ ushort smem[18432];
    const int K = 1024, T = 32;
    const int id = blockIdx.x;
    const int xcd = id & 7, r_ = id >> 3;
    const int bm = (xcd * 4 + r_ / 24) * 128;
    const int bn = r_ % 24;
    const int tid = threadIdx.x;
    const int wave = tid >> 6, lane = tid & 63;
    const int quad = lane >> 4, l15 = lane & 15;
    const int wm = (wave >> 1) * 64, wn = (wave & 1) * 64;

    const int s0 = tid, s1 = tid + 256;
    const int row0 = s0 >> 2, src0 = (s0 & 3) ^ (row0 & 3);
    const int row1 = s1 >> 2, src1 = (s1 & 3) ^ (row1 & 3);

    floatx4 acc[4][4];
    floatx4 z4 = {0.f, 0.f, 0.f, 0.f};
    for (int mi = 0; mi < 4; mi++)
        for (int ni = 0; ni < 4; ni++) acc[mi][ni] = z4;

    const ushort* Ap0 = A + (size_t)(bm + row0) * K + src0 * 8;
    const ushort* Ap1 = A + (size_t)(bm + row1) * K + src1 * 8;
    const ushort* Bp0 = Bt + (size_t)(bn * 128 + row0) * K + src0 * 8;
    const ushort* Bp1 = Bt + (size_t)(bn * 128 + row1) * K + src1 * 8;

    ushort* As = smem;          // [2][4096]
    ushort* Bs = smem + 8192;   // [2][4096]

    cp16(Ap0, &As[wave * 512]);
    cp16(Ap1, &As[2048 + wave * 512]);
    cp16(Bp0, &Bs[wave * 512]);
    cp16(Bp1, &Bs[2048 + wave * 512]);

    for (int t = 0; t < T; t++) {
        __syncthreads();
        if (t + 1 < T) {
            const int nb = (t + 1) & 1;
            const int k0n = (t + 1) << 5;
            cp16(Ap0 + k0n, &As[nb * 4096 + wave * 512]);
            cp16(Ap1 + k0n, &As[nb * 4096 + 2048 + wave * 512]);
            cp16(Bp0 + k0n, &Bs[nb * 4096 + wave * 512]);
            cp16(Bp1 + k0n, &Bs[nb * 4096 + 2048 + wave * 512]);
        }
        const ushort* Ab = As + (t & 1) * 4096;
        const ushort* Bb = Bs + (t & 1) * 4096;
        short8 af[4], bfr[4];
        for (int mi = 0; mi < 4; mi++) {
            int ra = wm + mi * 16 + l15;
            af[mi] = *(const short8*)&Ab[ra * 32 + ((quad ^ (ra & 3)) << 3)];
        }
        for (int ni = 0; ni < 4; ni++) {
            int rb = wn + ni * 16 + l15;
            bfr[ni] = *(const short8*)&Bb[rb * 32 + ((quad ^ (rb & 3)) << 3)];
        }
        for (int mi = 0; mi < 4; mi++)
            for (int ni = 0; ni < 4; ni++)
                acc[mi][ni] = __builtin_amdgcn_mfma_f32_16x16x32_bf16(
                    af[mi], bfr[ni], acc[mi][ni], 0, 0, 0);
    }

    const int col_base = bn * 128 + wn;
    const int type = col_base >> 10;             // 0=q, 1=k, 2=v
    const int h = (col_base & 1023) >> 6;
    const int row_base = bm + wm;

    if (type < 2) {
        ushort* dst = (type == 0) ? Qt : Kt;
        for (int mi = 0; mi < 4; mi++) {
            for (int r = 0; r < 4; r++) {
                float ss = 0.f;
                for (int ni = 0; ni < 4; ni++) ss += acc[mi][ni][r] * acc[mi][ni][r];
                for (int off = 1; off < 16; off <<= 1) ss += __shfl_xor(ss, off);
                float inv = rsqrtf(fmaxf(ss, 1e-24f));
                int rg = row_base + mi * 16 + quad * 4 + r;
                int bb = rg >> 11, n = rg & 2047;
                size_t orow = ((size_t)(bb * 16 + h) * 2048 + n) * 64;
                for (int ni = 0; ni < 4; ni++)
                    dst[orow + ni * 16 + l15] = f2bf(acc[mi][ni][r] * inv);
            }
        }
    } else {
        __syncthreads();
        ushort* tr = smem + wave * 4608;   // 64 x 72
        for (int mi = 0; mi < 4; mi++)
            for (int ni = 0; ni < 4; ni++)
                for (int r = 0; r < 4; r++) {
                    int row_l = mi * 16 + quad * 4 + r;   // n_loc
                    int col_l = ni * 16 + l15;            // d
                    tr[col_l * 72 + row_l] = f2bf(acc[mi][ni][r]);
                }
        int bb = row_base >> 11, n0 = row_base & 2047;
        size_t vbase = ((size_t)(bb * 16 + h) * 32 + (n0 >> 6)) * 4096;
        const int dl = lane >> 3, nc = (lane & 7) * 8;
        for (int i = 0; i < 8; i++) {
            int d = dl + i * 8;
            short8 val = *(const short8*)&tr[d * 72 + nc];
            *(short8*)&Vb[vbase + (size_t)d * 64 + nc] = val;
        }
    }
}

// ---------------------------------------------------------------------------
// Kernel 3: MFMA GEMM (out-proj) — 64x64 tiles, grid 1024 = 4 blocks/CU.
// ---------------------------------------------------------------------------
__global__ __launch_bounds__(256) void gemm_out(const ushort* __restrict__ A,
                                                const ushort* __restrict__ Bt,
                                                float* __restrict__ C) {
    __shared__ ushort As[2][64 * 32];
    __shared__ ushort Bs[2][64 * 32];
    const int K = 1024, N = 1024;
    const int id = blockIdx.x;             // 0..1023
    const int xcd = id & 7, r_ = id >> 3;  // r_ 0..127
    const int bm = (xcd * 8 + (r_ >> 4)) * 64;
    const int bn = (r_ & 15) * 64;
    const int tid = threadIdx.x;
    const int wave = tid >> 6, lane = tid & 63;
    const int quad = lane >> 4, l15 = lane & 15;
    const int wm = (wave >> 1) * 32, wn = (wave & 1) * 32;

    const int row0 = tid >> 2, src0 = (tid & 3) ^ (row0 & 3);

    floatx4 acc[2][2];
    floatx4 z4 = {0.f, 0.f, 0.f, 0.f};
    for (int mi = 0; mi < 2; mi++)
        for (int ni = 0; ni < 2; ni++) acc[mi][ni] = z4;

    const ushort* Ap0 = A + (size_t)(bm + row0) * K + src0 * 8;
    const ushort* Bp0 = Bt + (size_t)(bn + row0) * K + src0 * 8;

    const int T = K >> 5;
    cp16(Ap0, &As[0][wave * 512]);
    cp16(Bp0, &Bs[0][wave * 512]);

    for (int t = 0; t < T; t++) {
        __syncthreads();
        if (t + 1 < T) {
            const int nb = (t + 1) & 1;
            const int k0n = (t + 1) << 5;
            cp16(Ap0 + k0n, &As[nb][wave * 512]);
            cp16(Bp0 + k0n, &Bs[nb][wave * 512]);
        }
        const ushort* Ab = As[t & 1];
        const ushort* Bb = Bs[t & 1];
        short8 af[2], bfr[2];
        for (int mi = 0; mi < 2; mi++) {
            int ra = wm + mi * 16 + l15;
            af[mi] = *(const short8*)&Ab[ra * 32 + ((quad ^ (ra & 3)) << 3)];
        }
        for (int ni = 0; ni < 2; ni++) {
            int rb = wn + ni * 16 + l15;
            bfr[ni] = *(const short8*)&Bb[rb * 32 + ((quad ^ (rb & 3)) << 3)];
        }
        for (int mi = 0; mi < 2; mi++)
            for (int ni = 0; ni < 2; ni++)
                acc[mi][ni] = __builtin_amdgcn_mfma_f32_16x16x32_bf16(
                    af[mi], bfr[ni], acc[mi][ni], 0, 0, 0);
    }
    for (int mi = 0; mi < 2; mi++)
        for (int ni = 0; ni < 2; ni++)
            for (int r = 0; r < 4; r++) {
                int row = bm + wm + mi * 16 + quad * 4 + r;
                int col = bn + wn + ni * 16 + l15;
                C[(size_t)row * N + col] = acc[mi][ni][r];
            }
}

// ---------------------------------------------------------------------------
// Kernel 4: causal flash attention v10 (measured local optimum; 7 structural
// variants all land 44-45 µs -> serialized MFMA->softmax->P-LDS->MFMA chain
// floor). PAIRED grid 512 (33 k-tiles/block exact), XCD-local decode,
// conflict-free Ps (stride 64, 16B-chunk XOR), single-barrier async dbuf.
// ---------------------------------------------------------------------------
#define LOG2E8 11.541560327111707f   // 8 * log2(e)

__global__ __launch_bounds__(256) void flash_attn(const ushort* __restrict__ Qt,
                                                  const ushort* __restrict__ Kt,
                                                  const ushort* __restrict__ Vb,
                                                  ushort* __restrict__ O) {
    const int id = blockIdx.x;
    const int xcd = id & 7, r_ = id >> 3;
    const int bh = xcd * 4 + (r_ >> 4);
    const int pairi = r_ & 15;
    const int b = bh >> 4, h = bh & 15;
    const int tid = threadIdx.x;
    const int wave = tid >> 6, lane = tid & 63;
    const int quad = lane >> 4, l15 = lane & 15;

    __shared__ ushort Ks[2][64 * 64];
    __shared__ ushort Vs[2][64 * 64];
    __shared__ ushort Ps[4][16 * 64];   // stride 64, chunk-XOR swizzled

    const int ch0 = tid, ch1 = tid + 256;
    const int r0 = ch0 >> 3, sg0 = (ch0 & 7) ^ (r0 & 7);
    const int r1 = ch1 >> 3, sg1 = (ch1 & 7) ^ (r1 & 7);

    const ushort* Kp0 = Kt + ((size_t)bh * 2048 + r0) * 64 + sg0 * 8;
    const ushort* Kp1 = Kt + ((size_t)bh * 2048 + r1) * 64 + sg1 * 8;
    const ushort* Vp0 = Vb + (size_t)bh * 131072 + r0 * 64 + sg0 * 8;
    const ushort* Vp1 = Vb + (size_t)bh * 131072 + r1 * 64 + sg1 * 8;

    floatx4 z4 = {0.f, 0.f, 0.f, 0.f};

    for (int pass = 0; pass < 2; pass++) {
        const int qt = pass ? (31 - pairi) : pairi;
        const int q0 = qt * 64;

        const ushort* Qp = Qt + ((size_t)bh * 2048 + q0 + wave * 16 + l15) * 64;
        short8 qf0 = *(const short8*)(Qp + quad * 8);
        short8 qf1 = *(const short8*)(Qp + 32 + quad * 8);

        float rs_acc[4] = {0.f, 0.f, 0.f, 0.f};
        floatx4 o_acc[4];
        for (int ni = 0; ni < 4; ni++) o_acc[ni] = z4;

        __syncthreads();  // prior pass's LDS readers done before re-staging buf0
        cp16(Kp0, &Ks[0][wave * 512]);
        cp16(Kp1, &Ks[0][2048 + wave * 512]);
        cp16(Vp0, &Vs[0][wave * 512]);
        cp16(Vp1, &Vs[0][2048 + wave * 512]);

        for (int kt = 0; kt <= qt; kt++) {
            __syncthreads();                     // drains cp16(kt) -> published
            if (kt < qt) {                       // prefetch kt+1 during compute
                const int nb2 = (kt + 1) & 1;
                const size_t to = (size_t)(kt + 1) * 4096;
                cp16(Kp0 + to, &Ks[nb2][wave * 512]);
                cp16(Kp1 + to, &Ks[nb2][2048 + wave * 512]);
                cp16(Vp0 + to, &Vs[nb2][wave * 512]);
                cp16(Vp1 + to, &Vs[nb2][2048 + wave * 512]);
            }
            const ushort* Kb = Ks[kt & 1];
            const ushort* Vb_ = Vs[kt & 1];

            floatx4 s_acc[4];
            for (int ni = 0; ni < 4; ni++) s_acc[ni] = z4;
            for (int ni = 0; ni < 4; ni++) {
                int rb = ni * 16 + l15;
                short8 kf0 = *(const short8*)&Kb[rb * 64 + ((quad ^ (rb & 7)) << 3)];
                short8 kf1 = *(const short8*)&Kb[rb * 64 + (((quad + 4) ^ (rb & 7)) << 3)];
                s_acc[ni] = __builtin_amdgcn_mfma_f32_16x16x32_bf16(qf0, kf0, s_acc[ni], 0, 0, 0);
                s_acc[ni] = __builtin_amdgcn_mfma_f32_16x16x32_bf16(qf1, kf1, s_acc[ni], 0, 0, 0);
            }

            const bool diag = (kt == qt);
            for (int ni = 0; ni < 4; ni++) {
                const int col_loc = ni * 16 + l15;
                const int chnk = col_loc >> 3;
                for (int r = 0; r < 4; r++) {
                    const int row_l = quad * 4 + r;
                    float e = __builtin_amdgcn_exp2f(
                        fmaf(s_acc[ni][r], LOG2E8, -LOG2E8));
                    if (diag && col_loc > wave * 16 + row_l) e = 0.f;
                    rs_acc[r] += e;
                    Ps[wave][row_l * 64 + (((chnk ^ (row_l & 7)) << 3) | (col_loc & 7))] =
                        f2bf_rtz(e);
                }
            }

            short8 pa0 = *(const short8*)&Ps[wave][l15 * 64 + ((quad ^ (l15 & 7)) << 3)];
            short8 pa1 = *(const short8*)&Ps[wave][l15 * 64 + (((quad + 4) ^ (l15 & 7)) << 3)];
            for (int ni = 0; ni < 4; ni++) {
                int rv = ni * 16 + l15;
                short8 v0 = *(const short8*)&Vb_[rv * 64 + ((quad ^ (rv & 7)) << 3)];
                short8 v1 = *(const short8*)&Vb_[rv * 64 + (((quad + 4) ^ (rv & 7)) << 3)];
                o_acc[ni] = __builtin_amdgcn_mfma_f32_16x16x32_bf16(pa0, v0, o_acc[ni], 0, 0, 0);
                o_acc[ni] = __builtin_amdgcn_mfma_f32_16x16x32_bf16(pa1, v1, o_acc[ni], 0, 0, 0);
            }
        }

        for (int r = 0; r < 4; r++) {
            float rs = rs_acc[r];
            for (int off = 1; off < 16; off <<= 1) rs += __shfl_xor(rs, off);
            float inv = 1.0f / rs;
            int grow = q0 + wave * 16 + quad * 4 + r;
            size_t rowbase = ((size_t)b * 2048 + grow) * 1024 + h * 64;
            for (int ni = 0; ni < 4; ni++)
                O[rowbase + ni * 16 + l15] = f2bf(o_acc[ni][r] * inv);
        }
    }
}

// ---------------------------------------------------------------------------
extern "C" void kernel_launch(void* const* d_in, const int* in_sizes, int n_in,
                              void* d_out, int out_size, void* d_ws, size_t ws_size,
                              hipStream_t stream) {
    const float* x = (const float*)d_in[0];
    const float* ln_w = (const float*)d_in[1];
    const float* ln_b = (const float*)d_in[2];
    const float* W_qkv = (const float*)d_in[3];
    const float* W_out = (const float*)d_in[4];

    char* w = (char*)d_ws;
    // obuf ALIASES xn: xn is dead after gemm_qkv_fused's last read; flash
    // writes obuf strictly afterwards (stream-ordered). ws = 40 MiB.
    ushort* xn    = (ushort*)(w);                          // 8 MiB
    ushort* obuf  = (ushort*)(w);                          // 8 MiB (alias)
    ushort* WqkvT = (ushort*)(w + (8ull << 20));           // 6 MiB
    ushort* WoutT = (ushort*)(w + (14ull << 20));          // 2 MiB
    ushort* Vb    = (ushort*)(w + (16ull << 20));          // 8 MiB
    ushort* Qt    = (ushort*)(w + (24ull << 20));          // 8 MiB
    ushort* Kt    = (ushort*)(w + (32ull << 20));          // 8 MiB -> 40 MiB total

    prep_w_ln<<<8192, 256, 0, stream>>>(W_qkv, W_out, WqkvT, WoutT, x, ln_w, ln_b, xn);
    gemm_qkv_fused<<<768, 256, 0, stream>>>(xn, WqkvT, Qt, Kt, Vb);
    flash_attn<<<512, 256, 0, stream>>>(Qt, Kt, Vb, obuf);
    gemm_out<<<1024, 256, 0, stream>>>(obuf, WoutT, (float*)d_out);
}